// Round 6
// baseline (255.335 us; speedup 1.0000x reference)
//
#include <hip/hip_runtime.h>

typedef _Float16 half_t;
typedef __fp16   fp16x2 __attribute__((ext_vector_type(2)));
typedef _Float16 half4_t __attribute__((ext_vector_type(4)));
typedef _Float16 half8   __attribute__((ext_vector_type(8)));
typedef float    f32x4   __attribute__((ext_vector_type(4)));
typedef unsigned short u16x8 __attribute__((ext_vector_type(8)));

#define KP_S    0.057735026918962574f  // 0.1/sqrt(3)
#define INV_EXT 11.547005383792515f    // 1/(0.05*sqrt(3))
#define GPITCH  3616                   // G bytes/query: 64*28*2 data + 32 pad (mod128=32 -> uniform banks)
#define NBLK    512                    // persistent blocks = 2/CU exactly
#define NTILE   2500                   // 40000 queries / 16 per tile

union H8 { half8 v; fp16x2 h2[4]; };
union H4 { half4_t v; fp16x2 h2[2]; };

// WT[o][k], k = i*28 + l (fp16); l==27 zero pad column mirrors G's pitch-28 pad.
__global__ void build_wt(const float* __restrict__ W, half_t* __restrict__ WT) {
    int t = blockIdx.x * 256 + threadIdx.x;       // 64*1792 = 114688 exact
    if (t >= 64 * 1792) return;
    int o = t / 1792, k = t - o * 1792;
    int i = k / 28,   l = k - i * 28;
    WT[t] = (l < 27) ? (half_t)W[(l * 64 + i) * 64 + o] : (half_t)0.f;
}

// issue x-gather for both of this wave's queries into a 64-float register array
#define ISSUE_XV(BUF, XV) do {                                                 \
    u16x8 idA = *(const u16x8*)&idx_lds[BUF][2 * wid][8 * g];                  \
    u16x8 idB = *(const u16x8*)&idx_lds[BUF][2 * wid + 1][8 * g];              \
    _Pragma("unroll")                                                          \
    for (int j = 0; j < 8; ++j) {                                              \
        const float* pa = x + (int)idA[j] * 64 + lr;                           \
        const float* pb = x + (int)idB[j] * 64 + lr;                           \
        _Pragma("unroll")                                                      \
        for (int nt = 0; nt < 4; ++nt) {                                       \
            XV[nt * 8 + j]      = pa[16 * nt];                                 \
            XV[32 + nt * 8 + j] = pb[16 * nt];                                 \
        }                                                                      \
    }                                                                          \
} while (0)

#define BODY(T, TN, CUR, XVIN, XVOUT) do {                                     \
    /* (a) prefetch inds for tile TN */                                        \
    const int nn   = (TN) * 16 + aq;                                           \
    const int idxN = inds[nn * 32 + ah];                                       \
    /* (b) phase C for tile T: per-lane w, 8 MFMAs/query, dump G */            \
    _Pragma("unroll")                                                          \
    for (int qq = 0; qq < 2; ++qq) {                                           \
        const int q = wid * 2 + qq;                                            \
        float w0v[8], w1v[8];                                                  \
        _Pragma("unroll")                                                      \
        for (int j = 0; j < 8; ++j) {                                          \
            f32x4 nb = nbr_lds[CUR][q][8 * g + j];                             \
            float dx = nb.x - kx0, dy = nb.y - ky0, dz = nb.z - kz0;           \
            w0v[j] = fmaxf(fmaf(__builtin_amdgcn_sqrtf(dx*dx + dy*dy + dz*dz), -INV_EXT, 1.f), 0.f); \
            float ex = nb.x - kx1, ey = nb.y - ky1, ez = nb.z - kz1;           \
            w1v[j] = fmaxf(fmaf(__builtin_amdgcn_sqrtf(ex*ex + ey*ey + ez*ez), -INV_EXT, cbias), 0.f); \
        }                                                                      \
        H8 A0, A1;                                                             \
        _Pragma("unroll")                                                      \
        for (int p = 0; p < 4; ++p) {                                          \
            A0.h2[p] = __builtin_amdgcn_cvt_pkrtz(w0v[2*p], w0v[2*p+1]);       \
            A1.h2[p] = __builtin_amdgcn_cvt_pkrtz(w1v[2*p], w1v[2*p+1]);       \
        }                                                                      \
        char* gq = g_mem + q * GPITCH;                                         \
        _Pragma("unroll")                                                      \
        for (int nt = 0; nt < 4; ++nt) {                                       \
            H8 B;                                                              \
            _Pragma("unroll")                                                  \
            for (int p = 0; p < 4; ++p)                                        \
                B.h2[p] = __builtin_amdgcn_cvt_pkrtz(XVIN[qq*32 + nt*8 + 2*p], \
                                                     XVIN[qq*32 + nt*8 + 2*p + 1]); \
            f32x4 z = {0.f, 0.f, 0.f, 0.f};                                    \
            f32x4 c0 = __builtin_amdgcn_mfma_f32_16x16x32_f16(A0.v, B.v, z, 0, 0, 0); \
            f32x4 c1 = __builtin_amdgcn_mfma_f32_16x16x32_f16(A1.v, B.v, z, 0, 0, 0); \
            const int ic = 16 * nt + lr;                                       \
            H4 h0;                                                             \
            h0.h2[0] = __builtin_amdgcn_cvt_pkrtz(c0[0], c0[1]);               \
            h0.h2[1] = __builtin_amdgcn_cvt_pkrtz(c0[2], c0[3]);               \
            *(half4_t*)(gq + 2 * (ic * 28 + 4 * g)) = h0.v;                    \
            if (4 * g < 12) {                                                  \
                H4 h1;                                                         \
                h1.h2[0] = __builtin_amdgcn_cvt_pkrtz(c1[0], c1[1]);           \
                h1.h2[1] = __builtin_amdgcn_cvt_pkrtz(c1[2], c1[3]);           \
                *(half4_t*)(gq + 2 * (ic * 28 + 16 + 4 * g)) = h1.v;           \
            }                                                                  \
        }                                                                      \
    }                                                                          \
    /* (c) nbr gather for TN + idx store */                                    \
    f32x4 vN;                                                                  \
    vN.x = s_pts[idxN * 3 + 0] - q_pts[nn * 3 + 0];                            \
    vN.y = s_pts[idxN * 3 + 1] - q_pts[nn * 3 + 1];                            \
    vN.z = s_pts[idxN * 3 + 2] - q_pts[nn * 3 + 2];                            \
    vN.w = 0.f;                                                                \
    idx_lds[(CUR) ^ 1][aq][ah] = (unsigned short)idxN;                         \
    __syncthreads();                                        /* (d) */          \
    ISSUE_XV((CUR) ^ 1, XVOUT);                             /* (e) */          \
    /* (f) phase D for T: fx[16,64] = G @ WT^T, wave = (o-tile, K-half) */     \
    const half_t* wrow = WT + (16 * ot + lr) * 1792 + kh * 896 + 8 * g;        \
    const char*   gb   = g_mem + lr * GPITCH + kh * 1792;                      \
    f32x4 accA = {0.f, 0.f, 0.f, 0.f}, accB = {0.f, 0.f, 0.f, 0.f};            \
    _Pragma("unroll 7")                                                        \
    for (int s = 0; s < 28; s += 2) {                                          \
        half8 aA = *(const half8*)(gb + 64 * s + 16 * g);                      \
        half8 bA = *(const half8*)(wrow + 32 * s);                             \
        accA = __builtin_amdgcn_mfma_f32_16x16x32_f16(aA, bA, accA, 0, 0, 0);  \
        half8 aB = *(const half8*)(gb + 64 * (s + 1) + 16 * g);                \
        half8 bB = *(const half8*)(wrow + 32 * (s + 1));                       \
        accB = __builtin_amdgcn_mfma_f32_16x16x32_f16(aB, bB, accB, 0, 0, 0);  \
    }                                                                          \
    f32x4 acc = accA + accB;                                                   \
    if (kh) *(f32x4*)&red[ot][lane] = acc;                                     \
    nbr_lds[(CUR) ^ 1][aq][ah] = vN;                        /* (g) */          \
    __syncthreads();                                        /* (h) */          \
    if (!kh) {                                              /* (i) */          \
        f32x4 p = red[ot][lane];                                               \
        const int o = 16 * ot + lr;                                            \
        _Pragma("unroll")                                                      \
        for (int r = 0; r < 4; ++r)                                            \
            out[((T) * 16 + 4 * g + r) * 64 + o] = acc[r] + p[r];              \
    }                                                                          \
} while (0)

__global__ __launch_bounds__(512, 4) void kpconv(
    const float* __restrict__ q_pts, const float* __restrict__ s_pts,
    const int*   __restrict__ inds,  const float* __restrict__ x,
    const half_t* __restrict__ WT,   float* __restrict__ out)
{
    // LDS: 57856 + 2048 + 16384 + 4096 = 80384 B -> 2 blocks/CU (16 waves/CU)
    __shared__ __align__(16) char   g_mem[16 * GPITCH];          // G[q][i*28+l] fp16
    __shared__ __align__(16) unsigned short idx_lds[2][16][32];  // double-buffered
    __shared__ __align__(16) f32x4  nbr_lds[2][16][32];          // double-buffered
    __shared__ __align__(16) f32x4  red[4][64];                  // phase-D K-reduction

    const int tid  = threadIdx.x;
    const int lane = tid & 63, wid = tid >> 6;
    const int lr   = lane & 15, g = lane >> 4;
    const int aq   = tid >> 5,  ah = tid & 31;      // phase-A mapping: 16q x 32h
    const int ot   = wid & 3,   kh = wid >> 2;      // phase-D wave role

    // this lane's two kernel points: l0 = lr (always valid), l1 = lr+16 (>=27 -> w=0)
    const float kx0 = (float)((lr / 3) % 3 - 1) * KP_S;
    const float ky0 = (float)( lr / 9      - 1) * KP_S;
    const float kz0 = (float)( lr % 3      - 1) * KP_S;
    const int   l1  = lr + 16;
    const float kx1 = (float)((l1 / 3) % 3 - 1) * KP_S;
    const float ky1 = (float)( l1 / 9      - 1) * KP_S;
    const float kz1 = (float)( l1 % 3      - 1) * KP_S;
    const float cbias = (l1 < 27) ? 1.f : -1.f;     // forces w1=0 for pad rows

    // ---- prologue: phase A for first tile -> buffer 0, then issue its x-gather ----
    {
        int n   = blockIdx.x * 16 + aq;
        int idx = inds[n * 32 + ah];
        idx_lds[0][aq][ah] = (unsigned short)idx;
        f32x4 v;
        v.x = s_pts[idx * 3 + 0] - q_pts[n * 3 + 0];
        v.y = s_pts[idx * 3 + 1] - q_pts[n * 3 + 1];
        v.z = s_pts[idx * 3 + 2] - q_pts[n * 3 + 2];
        v.w = 0.f;
        nbr_lds[0][aq][ah] = v;
    }
    __syncthreads();

    float xvA[64], xvB[64];
    ISSUE_XV(0, xvA);

    int cur = 0, useA = 1;
    for (int t = blockIdx.x; t < NTILE; t += NBLK) {
        int tn = (t + NBLK < NTILE) ? t + NBLK : t;   // clamp: last iter re-fetches self
        if (useA) { BODY(t, tn, cur, xvA, xvB); }
        else      { BODY(t, tn, cur, xvB, xvA); }
        useA ^= 1;
        cur  ^= 1;
    }
}

extern "C" void kernel_launch(void* const* d_in, const int* in_sizes, int n_in,
                              void* d_out, int out_size, void* d_ws, size_t ws_size,
                              hipStream_t stream) {
    const float* q_pts = (const float*)d_in[0];
    const float* s_pts = (const float*)d_in[1];
    const int*   inds  = (const int*)d_in[2];
    const float* x     = (const float*)d_in[3];
    const float* W     = (const float*)d_in[4];
    float* out = (float*)d_out;
    half_t* WT = (half_t*)d_ws;                 // 64*1792*2 = 229376 B

    build_wt<<<448, 256, 0, stream>>>(W, WT);   // 448*256 = 114688 exact
    kpconv<<<NBLK, 512, 0, stream>>>(q_pts, s_pts, inds, x, WT, out);
}

// Round 7
// 99.368 us; speedup vs baseline: 2.5696x; 2.5696x over previous
//
#include <hip/hip_runtime.h>

typedef _Float16 half_t;
typedef __fp16   fp16x2 __attribute__((ext_vector_type(2)));
typedef _Float16 half4_t __attribute__((ext_vector_type(4)));
typedef _Float16 half8   __attribute__((ext_vector_type(8)));
typedef float    f32x4   __attribute__((ext_vector_type(4)));
typedef unsigned short u16x8 __attribute__((ext_vector_type(8)));

#define KP_S    0.057735026918962574f  // 0.1/sqrt(3)
#define INV_EXT 11.547005383792515f    // 1/(0.05*sqrt(3))
#define GPITCH  3616                   // G bytes/query: 64*28*2 data + 32 pad (mod128=32 -> uniform banks)
#define NBLK    512                    // persistent blocks = 2/CU exactly
#define NTILE   2500                   // 40000 queries / 16 per tile

union H8 { half8 v; fp16x2 h2[4]; };
union H4 { half4_t v; fp16x2 h2[2]; };

// WT[o][k], k = i*28 + l (fp16); l==27 zero pad column mirrors G's pitch-28 pad.
__global__ void build_wt(const float* __restrict__ W, half_t* __restrict__ WT) {
    int t = blockIdx.x * 256 + threadIdx.x;       // 64*1792 = 114688 exact
    if (t >= 64 * 1792) return;
    int o = t / 1792, k = t - o * 1792;
    int i = k / 28,   l = k - i * 28;
    WT[t] = (l < 27) ? (half_t)W[(l * 64 + i) * 64 + o] : (half_t)0.f;
}

// issue one query's x-gather (32 f32 in flight)
#define ISSUE_XV1(BUF, Q, XV) do {                                             \
    u16x8 id8 = *(const u16x8*)&idx_lds[BUF][Q][8 * g];                        \
    _Pragma("unroll")                                                          \
    for (int j = 0; j < 8; ++j) {                                              \
        const float* xp = x + (int)id8[j] * 64 + lr;                           \
        _Pragma("unroll")                                                      \
        for (int nt = 0; nt < 4; ++nt) XV[nt * 8 + j] = xp[16 * nt];           \
    }                                                                          \
} while (0)

// pack 32 f32 -> 4 half8 B-fragments (XV dies here)
#define PACK_B(XV, BF) do {                                                    \
    _Pragma("unroll")                                                          \
    for (int nt = 0; nt < 4; ++nt) {                                           \
        _Pragma("unroll")                                                      \
        for (int p = 0; p < 4; ++p)                                            \
            BF[nt].h2[p] = __builtin_amdgcn_cvt_pkrtz(XV[nt * 8 + 2 * p],      \
                                                      XV[nt * 8 + 2 * p + 1]); \
    }                                                                          \
} while (0)

// per-lane influence weights + stage-1 MFMAs + G dump for one query
#define MFMA_DUMP(Q, CUR, BF) do {                                             \
    float w0v[8], w1v[8];                                                      \
    _Pragma("unroll")                                                          \
    for (int j = 0; j < 8; ++j) {                                              \
        f32x4 nb = nbr_lds[CUR][Q][8 * g + j];                                 \
        float dx = nb.x - kx0, dy = nb.y - ky0, dz = nb.z - kz0;               \
        w0v[j] = fmaxf(fmaf(__builtin_amdgcn_sqrtf(dx*dx + dy*dy + dz*dz), -INV_EXT, 1.f), 0.f); \
        float ex = nb.x - kx1, ey = nb.y - ky1, ez = nb.z - kz1;               \
        w1v[j] = fmaxf(fmaf(__builtin_amdgcn_sqrtf(ex*ex + ey*ey + ez*ez), -INV_EXT, cbias), 0.f); \
    }                                                                          \
    H8 A0, A1;                                                                 \
    _Pragma("unroll")                                                          \
    for (int p = 0; p < 4; ++p) {                                              \
        A0.h2[p] = __builtin_amdgcn_cvt_pkrtz(w0v[2*p], w0v[2*p+1]);           \
        A1.h2[p] = __builtin_amdgcn_cvt_pkrtz(w1v[2*p], w1v[2*p+1]);           \
    }                                                                          \
    char* gq = g_mem + (Q) * GPITCH;                                           \
    _Pragma("unroll")                                                          \
    for (int nt = 0; nt < 4; ++nt) {                                           \
        f32x4 z = {0.f, 0.f, 0.f, 0.f};                                        \
        f32x4 c0 = __builtin_amdgcn_mfma_f32_16x16x32_f16(A0.v, BF[nt].v, z, 0, 0, 0); \
        f32x4 c1 = __builtin_amdgcn_mfma_f32_16x16x32_f16(A1.v, BF[nt].v, z, 0, 0, 0); \
        const int ic = 16 * nt + lr;                                           \
        H4 h0;                                                                 \
        h0.h2[0] = __builtin_amdgcn_cvt_pkrtz(c0[0], c0[1]);                   \
        h0.h2[1] = __builtin_amdgcn_cvt_pkrtz(c0[2], c0[3]);                   \
        *(half4_t*)(gq + 2 * (ic * 28 + 4 * g)) = h0.v;                        \
        if (4 * g < 12) {                                                      \
            H4 h1;                                                             \
            h1.h2[0] = __builtin_amdgcn_cvt_pkrtz(c1[0], c1[1]);               \
            h1.h2[1] = __builtin_amdgcn_cvt_pkrtz(c1[2], c1[3]);               \
            *(half4_t*)(gq + 2 * (ic * 28 + 16 + 4 * g)) = h1.v;               \
        }                                                                      \
    }                                                                          \
} while (0)

#define BODY(T, TN, CUR, XV) do {                                              \
    /* qA: pack B-frags (XV dies), then issue qB loads under qA compute */     \
    H8 BFA[4];                                                                 \
    PACK_B(XV, BFA);                                                           \
    float xvB[32];                                                             \
    ISSUE_XV1(CUR, 2 * wid + 1, xvB);                                          \
    const int nn   = (TN) * 16 + aq;                                           \
    const int idxN = inds[nn * 32 + ah];                                       \
    MFMA_DUMP(2 * wid, CUR, BFA);                                              \
    f32x4 vN;                                                                  \
    vN.x = s_pts[idxN * 3 + 0] - q_pts[nn * 3 + 0];                            \
    vN.y = s_pts[idxN * 3 + 1] - q_pts[nn * 3 + 1];                            \
    vN.z = s_pts[idxN * 3 + 2] - q_pts[nn * 3 + 2];                            \
    vN.w = 0.f;                                                                \
    H8 BFB[4];                                                                 \
    PACK_B(xvB, BFB);                                                          \
    MFMA_DUMP(2 * wid + 1, CUR, BFB);                                          \
    idx_lds[(CUR) ^ 1][aq][ah] = (unsigned short)idxN;                         \
    nbr_lds[(CUR) ^ 1][aq][ah] = vN;                                           \
    __syncthreads();                                                           \
    /* refill XV with next tile's qA under phase D */                          \
    ISSUE_XV1((CUR) ^ 1, 2 * wid, XV);                                         \
    /* phase D for T: fx[16,64] = G @ WT^T, wave = (o-tile, K-half) */         \
    const half_t* wrow = WT + (16 * ot + lr) * 1792 + kh * 896 + 8 * g;        \
    const char*   gb   = g_mem + lr * GPITCH + kh * 1792;                      \
    f32x4 accA = {0.f, 0.f, 0.f, 0.f}, accB = {0.f, 0.f, 0.f, 0.f};            \
    _Pragma("unroll 7")                                                        \
    for (int s = 0; s < 28; s += 2) {                                          \
        half8 aA = *(const half8*)(gb + 64 * s + 16 * g);                      \
        half8 bA = *(const half8*)(wrow + 32 * s);                             \
        accA = __builtin_amdgcn_mfma_f32_16x16x32_f16(aA, bA, accA, 0, 0, 0);  \
        half8 aB = *(const half8*)(gb + 64 * (s + 1) + 16 * g);                \
        half8 bB = *(const half8*)(wrow + 32 * (s + 1));                       \
        accB = __builtin_amdgcn_mfma_f32_16x16x32_f16(aB, bB, accB, 0, 0, 0);  \
    }                                                                          \
    f32x4 acc = accA + accB;                                                   \
    if (kh) *(f32x4*)&red[ot][lane] = acc;                                     \
    __syncthreads();                                                           \
    if (!kh) {                                                                 \
        f32x4 p = red[ot][lane];                                               \
        const int o = 16 * ot + lr;                                            \
        _Pragma("unroll")                                                      \
        for (int r = 0; r < 4; ++r)                                            \
            out[((T) * 16 + 4 * g + r) * 64 + o] = acc[r] + p[r];              \
    }                                                                          \
} while (0)

__global__ __launch_bounds__(512, 4) void kpconv(
    const float* __restrict__ q_pts, const float* __restrict__ s_pts,
    const int*   __restrict__ inds,  const float* __restrict__ x,
    const half_t* __restrict__ WT,   float* __restrict__ out)
{
    // LDS: 57856 + 2048 + 16384 + 4096 = 80384 B -> 2 blocks/CU (16 waves/CU)
    __shared__ __align__(16) char   g_mem[16 * GPITCH];          // G[q][i*28+l] fp16
    __shared__ __align__(16) unsigned short idx_lds[2][16][32];  // double-buffered
    __shared__ __align__(16) f32x4  nbr_lds[2][16][32];          // double-buffered
    __shared__ __align__(16) f32x4  red[4][64];                  // phase-D K-reduction

    const int tid  = threadIdx.x;
    const int lane = tid & 63, wid = tid >> 6;
    const int lr   = lane & 15, g = lane >> 4;
    const int aq   = tid >> 5,  ah = tid & 31;      // phase-A mapping: 16q x 32h
    const int ot   = wid & 3,   kh = wid >> 2;      // phase-D wave role

    // this lane's two kernel points: l0 = lr (always valid), l1 = lr+16 (>=27 -> w=0)
    const float kx0 = (float)((lr / 3) % 3 - 1) * KP_S;
    const float ky0 = (float)( lr / 9      - 1) * KP_S;
    const float kz0 = (float)( lr % 3      - 1) * KP_S;
    const int   l1  = lr + 16;
    const float kx1 = (float)((l1 / 3) % 3 - 1) * KP_S;
    const float ky1 = (float)( l1 / 9      - 1) * KP_S;
    const float kz1 = (float)( l1 % 3      - 1) * KP_S;
    const float cbias = (l1 < 27) ? 1.f : -1.f;     // forces w1=0 for pad rows

    // ---- prologue: phase A for first tile -> buffer 0, then issue qA x-gather ----
    {
        int n   = blockIdx.x * 16 + aq;
        int idx = inds[n * 32 + ah];
        idx_lds[0][aq][ah] = (unsigned short)idx;
        f32x4 v;
        v.x = s_pts[idx * 3 + 0] - q_pts[n * 3 + 0];
        v.y = s_pts[idx * 3 + 1] - q_pts[n * 3 + 1];
        v.z = s_pts[idx * 3 + 2] - q_pts[n * 3 + 2];
        v.w = 0.f;
        nbr_lds[0][aq][ah] = v;
    }
    __syncthreads();

    float xv[32];
    ISSUE_XV1(0, 2 * wid, xv);

    int cur = 0;
    for (int t = blockIdx.x; t < NTILE; t += NBLK) {
        int tn = (t + NBLK < NTILE) ? t + NBLK : t;   // clamp: last iter re-fetches self
        BODY(t, tn, cur, xv);
        cur ^= 1;
    }
}

extern "C" void kernel_launch(void* const* d_in, const int* in_sizes, int n_in,
                              void* d_out, int out_size, void* d_ws, size_t ws_size,
                              hipStream_t stream) {
    const float* q_pts = (const float*)d_in[0];
    const float* s_pts = (const float*)d_in[1];
    const int*   inds  = (const int*)d_in[2];
    const float* x     = (const float*)d_in[3];
    const float* W     = (const float*)d_in[4];
    float* out = (float*)d_out;
    half_t* WT = (half_t*)d_ws;                 // 64*1792*2 = 229376 B

    build_wt<<<448, 256, 0, stream>>>(W, WT);   // 448*256 = 114688 exact
    kpconv<<<NBLK, 512, 0, stream>>>(q_pts, s_pts, inds, x, WT, out);
}